// Round 1
// baseline (1447.104 us; speedup 1.0000x reference)
//
#include <hip/hip_runtime.h>
#include <cstdint>
#include <cstddef>

#pragma clang fp contract(off)

#define NB 32
#define NA 9
#define NH 128
#define NW 128
#define HW (NH*NW)            // 16384
#define NANCH (NA*HW)         // 147456
#define PRE_N 6000
#define POST_N 300
#define CAND_CAP 8192
#define NMS_T 0.7f

// Base anchor widths/heights (generate_anchors(16,[.5,1,2],[8,16,32])).
// All anchor centers are at (w*16+8, h*16+8) exactly (fp32-exact integers).
__constant__ float c_wa[9] = {184.f,368.f,736.f,128.f,256.f,512.f,88.f,176.f,352.f};
__constant__ float c_ha[9] = {96.f,192.f,384.f,128.f,256.f,512.f,176.f,352.f,704.f};

__device__ __forceinline__ float4 decode_clip(int a, int h, int w,
    float dx, float dy, float dlw, float dlh, float imh, float imw) {
  float wa = c_wa[a], ha = c_ha[a];
  float cx = (float)w * 16.0f + 8.0f;
  float cy = (float)h * 16.0f + 8.0f;
  float pcx = dx * wa + cx;
  float pcy = dy * ha + cy;
  float pw = expf(dlw) * wa;
  float ph = expf(dlh) * ha;
  float x1 = pcx - 0.5f * pw;
  float y1 = pcy - 0.5f * ph;
  float x2 = pcx + 0.5f * pw;
  float y2 = pcy + 0.5f * ph;
  float4 r;
  r.x = fminf(fmaxf(x1, 0.0f), imw - 1.0f);
  r.y = fminf(fmaxf(y1, 0.0f), imh - 1.0f);
  r.z = fminf(fmaxf(x2, 0.0f), imw - 1.0f);
  r.w = fminf(fmaxf(y2, 0.0f), imh - 1.0f);
  return r;
}

// picked box (x1..y2,a2) vs candidate v/ar: reference iou = inter / max(a_pick + a_cand - inter, 1e-6)
__device__ __forceinline__ bool sup_test(float4 v, float ar,
    float x1, float y1, float x2, float y2, float a2) {
  float xx1 = fmaxf(x1, v.x), yy1 = fmaxf(y1, v.y);
  float xx2 = fminf(x2, v.z), yy2 = fminf(y2, v.w);
  float iw = fmaxf(xx2 - xx1 + 1.0f, 0.0f);
  float ih = fmaxf(yy2 - yy1 + 1.0f, 0.0f);
  float inter = iw * ih;
  float iou = inter / fmaxf(a2 + ar - inter, 1e-6f);
  return iou > NMS_T;
}

// K1: decode+filter -> order-preserving uint key per anchor; 65536-bin histogram of key>>16.
__global__ __launch_bounds__(256) void k_keys(const float* __restrict__ cls,
    const float* __restrict__ dl, const float* __restrict__ info,
    unsigned* __restrict__ keys, unsigned* __restrict__ hist) {
  int hw = blockIdx.x * 256 + threadIdx.x;   // 0..16383
  int b = blockIdx.y;
  int h = hw >> 7, w = hw & 127;
  const float* dlb  = dl  + (size_t)b * (4*NA*HW);
  const float* clsb = cls + (size_t)b * (2*NA*HW);
  float imh = info[b*3+0], imw = info[b*3+1];
  float msz = 16.0f * info[b*3+2];
  unsigned* kb = keys + (size_t)b * NANCH;
  unsigned* hb = hist + ((size_t)b << 16);
  #pragma unroll
  for (int a = 0; a < 9; ++a) {
    float dx  = dlb[(a*4+0)*HW + hw];
    float dy  = dlb[(a*4+1)*HW + hw];
    float dw_ = dlb[(a*4+2)*HW + hw];
    float dh_ = dlb[(a*4+3)*HW + hw];
    float4 bx = decode_clip(a, h, w, dx, dy, dw_, dh_, imh, imw);
    float bw = bx.z - bx.x + 1.0f;
    float bh = bx.w - bx.y + 1.0f;
    float sc = clsb[(NA + a)*HW + hw];
    unsigned bits = __float_as_uint(sc);
    unsigned key = (bits & 0x80000000u) ? ~bits : (bits | 0x80000000u);
    if (!(bw >= msz && bh >= msz)) key = 0u;   // filtered == score NEG_INF
    kb[hw*9 + a] = key;
    atomicAdd(&hb[key >> 16], 1u);
  }
}

// K2: per image, find threshold kthr = bin<<16 such that count(key >= kthr) in [6000, ~6600].
__global__ __launch_bounds__(256) void k_select(const unsigned* __restrict__ hist,
                                                unsigned* __restrict__ kthr) {
  int b = blockIdx.x, tid = threadIdx.x;
  const unsigned* hb = hist + ((size_t)b << 16);
  __shared__ unsigned part[256];
  unsigned s = 0;
  const uint4* h4 = (const uint4*)(hb + tid * 256);
  for (int i = 0; i < 64; ++i) { uint4 vv = h4[i]; s += vv.x + vv.y + vv.z + vv.w; }
  part[tid] = s;
  __syncthreads();
  if (tid == 0) {
    unsigned cum = 0; int chunk = 0;
    for (int c = 255; c >= 0; --c) {
      if (cum + part[c] >= (unsigned)PRE_N) { chunk = c; break; }
      cum += part[c];
    }
    const unsigned* cbp = hb + chunk * 256;
    unsigned kt = 0;
    for (int i = 255; i >= 0; --i) {
      cum += cbp[i];
      if (cum >= (unsigned)PRE_N) { kt = ((unsigned)(chunk * 256 + i)) << 16; break; }
    }
    kthr[b] = kt;
  }
}

// K3: gather (key, ~idx) for key >= kthr (packed u64 sorts as score desc, idx asc).
__global__ __launch_bounds__(256) void k_gather(const unsigned* __restrict__ keys,
    const unsigned* __restrict__ kthr, unsigned* __restrict__ cnt,
    unsigned long long* __restrict__ cand) {
  int i = blockIdx.x * 256 + threadIdx.x;   // 0..147455
  int b = blockIdx.y;
  unsigned key = keys[(size_t)b * NANCH + i];
  if (key >= kthr[b] && key > 0u) {
    unsigned pos = atomicAdd(&cnt[b], 1u);
    if (pos < CAND_CAP)
      cand[(size_t)b * CAND_CAP + pos] =
          ((unsigned long long)key << 32) | (unsigned)(~i);
  }
}

// K4: per image, bitonic-sort 8192 u64 descending in LDS; decode boxes for top-6000.
__global__ __launch_bounds__(1024) void k_sort(unsigned long long* __restrict__ cand,
    const float* __restrict__ dl, const float* __restrict__ info,
    float4* __restrict__ boxes) {
  __shared__ unsigned long long sm[CAND_CAP];   // 64 KiB
  int b = blockIdx.x, tid = threadIdx.x;
  unsigned long long* cb = cand + (size_t)b * CAND_CAP;
  for (int t = tid; t < CAND_CAP; t += 1024) sm[t] = cb[t];
  for (int k = 2; k <= CAND_CAP; k <<= 1) {
    for (int j = k >> 1; j > 0; j >>= 1) {
      __syncthreads();
      for (int t = tid; t < CAND_CAP; t += 1024) {
        int p = t ^ j;
        if (p > t) {
          unsigned long long x = sm[t], y = sm[p];
          bool up = (t & k) == 0;              // descending overall
          if (up ? (x < y) : (x > y)) { sm[t] = y; sm[p] = x; }
        }
      }
    }
  }
  __syncthreads();
  const float* dlb = dl + (size_t)b * (4*NA*HW);
  float imh = info[b*3+0], imw = info[b*3+1];
  for (int t = tid; t < PRE_N; t += 1024) {
    unsigned long long ck = sm[t];
    cb[t] = ck;                                 // sorted order for k_nms validity
    float4 bx = make_float4(0.f, 0.f, 0.f, 0.f);
    if ((unsigned)(ck >> 32) != 0u) {
      int i = (int)(~(unsigned)(ck & 0xFFFFFFFFull));
      int a = i % 9, hw = i / 9;
      int h = hw >> 7, w = hw & 127;
      bx = decode_clip(a, h, w,
                       dlb[(a*4+0)*HW + hw], dlb[(a*4+1)*HW + hw],
                       dlb[(a*4+2)*HW + hw], dlb[(a*4+3)*HW + hw], imh, imw);
    }
    boxes[(size_t)b * PRE_N + t] = bx;
  }
}

// K5: greedy NMS, chunked. kept(i) iff no earlier-kept box has IoU > 0.7 with i.
__global__ __launch_bounds__(256) void k_nms(const unsigned long long* __restrict__ cand,
    const float4* __restrict__ boxes, float* __restrict__ out) {
  int b = blockIdx.x, tid = threadIdx.x;
  int lane = tid & 63, wv = tid >> 6;
  __shared__ float kx1[POST_N], ky1[POST_N], kx2[POST_N], ky2[POST_N], ka[POST_N];
  __shared__ int s_nk;
  if (tid == 0) s_nk = 0;
  __syncthreads();
  const unsigned long long* cb = cand + (size_t)b * CAND_CAP;
  const float4* bb = boxes + (size_t)b * PRE_N;
  float* ob = out + (size_t)b * (POST_N * 5);

  for (int base = 0; base < PRE_N; base += 256) {
    int i = base + tid;
    float4 v = make_float4(0.f, 0.f, 0.f, 0.f);
    bool alive = false;
    if (i < PRE_N) {
      unsigned long long ck = cb[i];
      if ((unsigned)(ck >> 32) != 0u) { alive = true; v = bb[i]; }
    }
    float ar = (v.z - v.x + 1.0f) * (v.w - v.y + 1.0f);
    int nk0 = s_nk;
    for (int k = 0; k < nk0 && alive; ++k)
      if (sup_test(v, ar, kx1[k], ky1[k], kx2[k], ky2[k], ka[k])) alive = false;
    int checked = nk0;
    for (int w = 0; w < 4; ++w) {
      __syncthreads();
      if (wv == w) {
        int nk = s_nk;
        for (int k = checked; k < nk && alive; ++k)
          if (sup_test(v, ar, kx1[k], ky1[k], kx2[k], ky2[k], ka[k])) alive = false;
        for (int l = 0; l < 64; ++l) {
          int la = __shfl(alive ? 1 : 0, l);
          if (la && nk < POST_N) {
            float bx1 = __shfl(v.x, l), by1 = __shfl(v.y, l);
            float bx2 = __shfl(v.z, l), by2 = __shfl(v.w, l);
            float ba  = __shfl(ar,  l);
            if (lane == l) {
              kx1[nk] = v.x; ky1[nk] = v.y; kx2[nk] = v.z; ky2[nk] = v.w; ka[nk] = ar;
              ob[nk*5+0] = (float)b;
              ob[nk*5+1] = v.x; ob[nk*5+2] = v.y; ob[nk*5+3] = v.z; ob[nk*5+4] = v.w;
            }
            if (lane > l && alive)
              if (sup_test(v, ar, bx1, by1, bx2, by2, ba)) alive = false;
            nk++;
          }
        }
        if (lane == 0) s_nk = nk;
      }
    }
    __syncthreads();
    if (s_nk >= POST_N) break;
  }
  __syncthreads();
  int nk = s_nk;
  for (int r = nk + tid; r < POST_N; r += 256) {
    ob[r*5+0] = (float)b;
    ob[r*5+1] = 0.f; ob[r*5+2] = 0.f; ob[r*5+3] = 0.f; ob[r*5+4] = 0.f;
  }
}

extern "C" void kernel_launch(void* const* d_in, const int* in_sizes, int n_in,
                              void* d_out, int out_size, void* d_ws, size_t ws_size,
                              hipStream_t stream) {
  const float* cls  = (const float*)d_in[0];   // (32, 18, 128, 128)
  const float* dl   = (const float*)d_in[1];   // (32, 36, 128, 128)
  const float* info = (const float*)d_in[2];   // (32, 3)
  float* out = (float*)d_out;                  // (32, 300, 5)
  char* ws = (char*)d_ws;

  // workspace layout (bytes)
  const size_t OFF_KEYS = 0;                       // 32*147456*4  = 18,874,368
  const size_t OFF_HIST = 18874368;                // 32*65536*4   =  8,388,608
  const size_t OFF_KTHR = 27262976;                // 128
  const size_t OFF_CNT  = 27263104;                // 128
  const size_t OFF_CAND = 27263232;                // 32*8192*8    =  2,097,152
  const size_t OFF_BOX  = 29360384;                // 32*6000*16   =  3,072,000
  const size_t WS_NEED  = 32432384;
  if (ws_size < WS_NEED) return;

  unsigned* keys = (unsigned*)(ws + OFF_KEYS);
  unsigned* hist = (unsigned*)(ws + OFF_HIST);
  unsigned* kthr = (unsigned*)(ws + OFF_KTHR);
  unsigned* cnt  = (unsigned*)(ws + OFF_CNT);
  unsigned long long* cand = (unsigned long long*)(ws + OFF_CAND);
  float4* boxes = (float4*)(ws + OFF_BOX);

  // zero hist + kthr + cnt + cand in one shot
  hipMemsetAsync(ws + OFF_HIST, 0, OFF_BOX - OFF_HIST, stream);

  dim3 g1(HW / 256, NB);
  k_keys<<<g1, 256, 0, stream>>>(cls, dl, info, keys, hist);
  k_select<<<NB, 256, 0, stream>>>(hist, kthr);
  dim3 g3(NANCH / 256, NB);
  k_gather<<<g3, 256, 0, stream>>>(keys, kthr, cnt, cand);
  k_sort<<<NB, 1024, 0, stream>>>(cand, dl, info, boxes);
  k_nms<<<NB, 256, 0, stream>>>(cand, boxes, out);
}

// Round 2
// 583.612 us; speedup vs baseline: 2.4796x; 2.4796x over previous
//
#include <hip/hip_runtime.h>
#include <cstdint>
#include <cstddef>

#pragma clang fp contract(off)

#define NB 32
#define NA 9
#define NH 128
#define NW 128
#define HW (NH*NW)            // 16384
#define NANCH (NA*HW)         // 147456
#define PRE_N 6000
#define POST_N 300
#define CAND_CAP 8192
#define NMS_T 0.7f
#define GX_GATHER 24          // blocks per image in k_gather

// Base anchor widths/heights (generate_anchors(16,[.5,1,2],[8,16,32])).
// All anchor centers are at (w*16+8, h*16+8) exactly (fp32-exact integers).
__constant__ float c_wa[9] = {184.f,368.f,736.f,128.f,256.f,512.f,88.f,176.f,352.f};
__constant__ float c_ha[9] = {96.f,192.f,384.f,128.f,256.f,512.f,176.f,352.f,704.f};

__device__ __forceinline__ float4 decode_clip(int a, int h, int w,
    float dx, float dy, float dlw, float dlh, float imh, float imw) {
  float wa = c_wa[a], ha = c_ha[a];
  float cx = (float)w * 16.0f + 8.0f;
  float cy = (float)h * 16.0f + 8.0f;
  float pcx = dx * wa + cx;
  float pcy = dy * ha + cy;
  float pw = expf(dlw) * wa;
  float ph = expf(dlh) * ha;
  float x1 = pcx - 0.5f * pw;
  float y1 = pcy - 0.5f * ph;
  float x2 = pcx + 0.5f * pw;
  float y2 = pcy + 0.5f * ph;
  float4 r;
  r.x = fminf(fmaxf(x1, 0.0f), imw - 1.0f);
  r.y = fminf(fmaxf(y1, 0.0f), imh - 1.0f);
  r.z = fminf(fmaxf(x2, 0.0f), imw - 1.0f);
  r.w = fminf(fmaxf(y2, 0.0f), imh - 1.0f);
  return r;
}

__device__ __forceinline__ unsigned score_key(float sc, float bw, float bh, float msz) {
  unsigned bits = __float_as_uint(sc);
  unsigned key = (bits & 0x80000000u) ? ~bits : (bits | 0x80000000u);
  if (!(bw >= msz && bh >= msz)) key = 0u;   // filtered == score NEG_INF
  return key;
}

// picked box vs candidate v/ar: reference iou = inter / max(a_pick + a_cand - inter, 1e-6)
__device__ __forceinline__ bool sup_test(float4 v, float ar,
    float x1, float y1, float x2, float y2, float a2) {
  float xx1 = fmaxf(x1, v.x), yy1 = fmaxf(y1, v.y);
  float xx2 = fminf(x2, v.z), yy2 = fminf(y2, v.w);
  float iw = fmaxf(xx2 - xx1 + 1.0f, 0.0f);
  float ih = fmaxf(yy2 - yy1 + 1.0f, 0.0f);
  float inter = iw * ih;
  float iou = inter / fmaxf(a2 + ar - inter, 1e-6f);
  return iou > NMS_T;
}

// K1: decode+filter -> order-preserving uint key per anchor. NO atomics.
// keys stored [a][hw] (coalesced); original anchor index = hw*9+a reconstructed later.
__global__ __launch_bounds__(256) void k_keys(const float* __restrict__ cls,
    const float* __restrict__ dl, const float* __restrict__ info,
    unsigned* __restrict__ keys) {
  int t = blockIdx.x * 256 + threadIdx.x;    // 0..4095
  int b = blockIdx.y;
  int hw0 = t * 4;                           // 4 consecutive hw, same row (W%4==0)
  int h = hw0 >> 7;
  const float* dlb  = dl  + (size_t)b * (4*NA*HW);
  const float* clsb = cls + (size_t)b * (2*NA*HW);
  float imh = info[b*3+0], imw = info[b*3+1];
  float msz = 16.0f * info[b*3+2];
  unsigned* kb = keys + (size_t)b * NANCH;
  #pragma unroll
  for (int a = 0; a < 9; ++a) {
    float4 dx4 = *(const float4*)&dlb[(a*4+0)*HW + hw0];
    float4 dy4 = *(const float4*)&dlb[(a*4+1)*HW + hw0];
    float4 dw4 = *(const float4*)&dlb[(a*4+2)*HW + hw0];
    float4 dh4 = *(const float4*)&dlb[(a*4+3)*HW + hw0];
    float4 sc4 = *(const float4*)&clsb[(NA+a)*HW + hw0];
    uint4 out;
    {
      float4 bx = decode_clip(a, h, (hw0+0)&127, dx4.x, dy4.x, dw4.x, dh4.x, imh, imw);
      out.x = score_key(sc4.x, bx.z-bx.x+1.0f, bx.w-bx.y+1.0f, msz);
    }
    {
      float4 bx = decode_clip(a, h, (hw0+1)&127, dx4.y, dy4.y, dw4.y, dh4.y, imh, imw);
      out.y = score_key(sc4.y, bx.z-bx.x+1.0f, bx.w-bx.y+1.0f, msz);
    }
    {
      float4 bx = decode_clip(a, h, (hw0+2)&127, dx4.z, dy4.z, dw4.z, dh4.z, imh, imw);
      out.z = score_key(sc4.z, bx.z-bx.x+1.0f, bx.w-bx.y+1.0f, msz);
    }
    {
      float4 bx = decode_clip(a, h, (hw0+3)&127, dx4.w, dy4.w, dw4.w, dh4.w, imh, imw);
      out.w = score_key(sc4.w, bx.z-bx.x+1.0f, bx.w-bx.y+1.0f, msz);
    }
    *(uint4*)&kb[a*HW + hw0] = out;
  }
}

// K2: 4096-bin histogram of key>>20, LDS-aggregated per block, flush nonzero bins.
__global__ __launch_bounds__(256) void k_hist1(const unsigned* __restrict__ keys,
                                                unsigned* __restrict__ hist) {
  __shared__ unsigned h[4096];
  int b = blockIdx.y, tid = threadIdx.x;
  for (int i = tid; i < 4096; i += 256) h[i] = 0;
  __syncthreads();
  const unsigned* kb = keys + (size_t)b * NANCH;
  for (int i = blockIdx.x * 256 + tid; i < NANCH; i += gridDim.x * 256)
    atomicAdd(&h[kb[i] >> 20], 1u);
  __syncthreads();
  unsigned* gb = hist + ((size_t)b << 12);
  for (int i = tid; i < 4096; i += 256) { unsigned v = h[i]; if (v) atomicAdd(&gb[i], v); }
}

// K3: per image find coarse bin B (top 12 bits) where from-top cumulative crosses PRE_N.
// selA[b*2] = B, selA[b*2+1] = count(key>>20 > B)
__global__ __launch_bounds__(256) void k_select1(const unsigned* __restrict__ hist,
                                                 unsigned* __restrict__ selA) {
  int b = blockIdx.x, tid = threadIdx.x;
  const unsigned* hb = hist + ((size_t)b << 12);
  __shared__ unsigned part[256];
  unsigned s = 0;
  for (int i = 0; i < 16; ++i) s += hb[tid*16 + i];
  part[tid] = s;
  __syncthreads();
  if (tid == 0) {
    unsigned cum = 0; int chunk = -1;
    for (int c = 255; c >= 0; --c) {
      if (cum + part[c] >= (unsigned)PRE_N) { chunk = c; break; }
      cum += part[c];
    }
    unsigned B = 0, cumAbove = cum;
    if (chunk >= 0) {
      for (int i = 15; i >= 0; --i) {
        unsigned v = hb[chunk*16 + i];
        if (cum + v >= (unsigned)PRE_N) { B = (unsigned)(chunk*16 + i); cumAbove = cum; break; }
        cum += v;
      }
    }
    selA[b*2+0] = B;
    selA[b*2+1] = cumAbove;
  }
}

// K4: refine — histogram bits[19:8] of keys whose top-12 == B.
__global__ __launch_bounds__(256) void k_hist2(const unsigned* __restrict__ keys,
    const unsigned* __restrict__ selA, unsigned* __restrict__ hist2) {
  __shared__ unsigned h[4096];
  int b = blockIdx.y, tid = threadIdx.x;
  for (int i = tid; i < 4096; i += 256) h[i] = 0;
  __syncthreads();
  unsigned B = selA[b*2+0];
  const unsigned* kb = keys + (size_t)b * NANCH;
  for (int i = blockIdx.x * 256 + tid; i < NANCH; i += gridDim.x * 256) {
    unsigned k = kb[i];
    if ((k >> 20) == B) atomicAdd(&h[(k >> 8) & 4095u], 1u);
  }
  __syncthreads();
  unsigned* gb = hist2 + ((size_t)b << 12);
  for (int i = tid; i < 4096; i += 256) { unsigned v = h[i]; if (v) atomicAdd(&gb[i], v); }
}

// K5: final 24-bit threshold thr such that count(key >= thr) crosses PRE_N.
__global__ __launch_bounds__(256) void k_select2(const unsigned* __restrict__ hist2,
    const unsigned* __restrict__ selA, unsigned* __restrict__ thr) {
  int b = blockIdx.x, tid = threadIdx.x;
  const unsigned* hb = hist2 + ((size_t)b << 12);
  __shared__ unsigned part[256];
  unsigned s = 0;
  for (int i = 0; i < 16; ++i) s += hb[tid*16 + i];
  part[tid] = s;
  __syncthreads();
  if (tid == 0) {
    unsigned B = selA[b*2+0], cum = selA[b*2+1];
    int chunk = -1;
    for (int c = 255; c >= 0; --c) {
      if (cum + part[c] >= (unsigned)PRE_N) { chunk = c; break; }
      cum += part[c];
    }
    unsigned t = 1u;
    if (chunk >= 0) {
      for (int i = 15; i >= 0; --i) {
        unsigned v = hb[chunk*16 + i];
        if (cum + v >= (unsigned)PRE_N) {
          t = (B << 20) | ((unsigned)(chunk*16 + i) << 8);
          break;
        }
        cum += v;
      }
    }
    if (t == 0u) t = 1u;
    thr[b] = t;
  }
}

// K6: gather (key, ~origidx) for key >= thr. Block-aggregated atomics:
// one atomicAdd per 256-item tile, counters padded to 256B.
__global__ __launch_bounds__(256) void k_gather(const unsigned* __restrict__ keys,
    const unsigned* __restrict__ thr, unsigned* __restrict__ cnt,
    unsigned long long* __restrict__ cand) {
  int b = blockIdx.y, tid = threadIdx.x;
  int lane = tid & 63, wv = tid >> 6;
  __shared__ unsigned wcnt[4], woff[4], blkbase;
  unsigned t_ = thr[b];
  const unsigned* kb = keys + (size_t)b * NANCH;
  unsigned long long* cb = cand + (size_t)b * CAND_CAP;
  unsigned* cp = cnt + (size_t)b * 64;
  const int PER_BLK = NANCH / GX_GATHER;      // 6144
  int base0 = blockIdx.x * PER_BLK;
  for (int it = 0; it < PER_BLK / 256; ++it) {
    int j = base0 + it * 256 + tid;
    unsigned key = kb[j];
    bool pass = key >= t_;
    unsigned long long mask = __ballot(pass);
    if (lane == 0) wcnt[wv] = (unsigned)__popcll(mask);
    __syncthreads();
    if (tid == 0) {
      unsigned s0 = 0;
      for (int w = 0; w < 4; ++w) { woff[w] = s0; s0 += wcnt[w]; }
      blkbase = s0 ? atomicAdd(cp, s0) : 0u;
    }
    __syncthreads();
    if (pass) {
      unsigned pos = blkbase + woff[wv] + (unsigned)__popcll(mask & ((1ull << lane) - 1ull));
      if (pos < CAND_CAP) {
        int a = j >> 14, hw = j & (HW - 1);
        unsigned oi = (unsigned)(hw * 9 + a);
        cb[pos] = ((unsigned long long)key << 32) | (unsigned)(~oi);
      }
    }
    __syncthreads();
  }
}

// K7: per image, bitonic-sort 8192 u64 descending in LDS; decode boxes for top-6000.
__global__ __launch_bounds__(1024) void k_sort(unsigned long long* __restrict__ cand,
    const float* __restrict__ dl, const float* __restrict__ info,
    float4* __restrict__ boxes) {
  __shared__ unsigned long long sm[CAND_CAP];   // 64 KiB
  int b = blockIdx.x, tid = threadIdx.x;
  unsigned long long* cb = cand + (size_t)b * CAND_CAP;
  for (int t = tid; t < CAND_CAP; t += 1024) sm[t] = cb[t];
  for (int k = 2; k <= CAND_CAP; k <<= 1) {
    for (int j = k >> 1; j > 0; j >>= 1) {
      __syncthreads();
      for (int t = tid; t < CAND_CAP; t += 1024) {
        int p = t ^ j;
        if (p > t) {
          unsigned long long x = sm[t], y = sm[p];
          bool up = (t & k) == 0;              // descending overall
          if (up ? (x < y) : (x > y)) { sm[t] = y; sm[p] = x; }
        }
      }
    }
  }
  __syncthreads();
  const float* dlb = dl + (size_t)b * (4*NA*HW);
  float imh = info[b*3+0], imw = info[b*3+1];
  for (int t = tid; t < PRE_N; t += 1024) {
    unsigned long long ck = sm[t];
    cb[t] = ck;                                 // sorted order for k_nms validity
    float4 bx = make_float4(0.f, 0.f, 0.f, 0.f);
    if ((unsigned)(ck >> 32) != 0u) {
      int i = (int)(~(unsigned)(ck & 0xFFFFFFFFull));
      int a = i % 9, hw = i / 9;
      int h = hw >> 7, w = hw & 127;
      bx = decode_clip(a, h, w,
                       dlb[(a*4+0)*HW + hw], dlb[(a*4+1)*HW + hw],
                       dlb[(a*4+2)*HW + hw], dlb[(a*4+3)*HW + hw], imh, imw);
    }
    boxes[(size_t)b * PRE_N + t] = bx;
  }
}

// K8: greedy NMS, chunked. kept(i) iff no earlier-kept box has IoU > 0.7 with i.
__global__ __launch_bounds__(256) void k_nms(const unsigned long long* __restrict__ cand,
    const float4* __restrict__ boxes, float* __restrict__ out) {
  int b = blockIdx.x, tid = threadIdx.x;
  int lane = tid & 63, wv = tid >> 6;
  __shared__ float kx1[POST_N], ky1[POST_N], kx2[POST_N], ky2[POST_N], ka[POST_N];
  __shared__ int s_nk;
  if (tid == 0) s_nk = 0;
  __syncthreads();
  const unsigned long long* cb = cand + (size_t)b * CAND_CAP;
  const float4* bb = boxes + (size_t)b * PRE_N;
  float* ob = out + (size_t)b * (POST_N * 5);

  for (int base = 0; base < PRE_N; base += 256) {
    int i = base + tid;
    float4 v = make_float4(0.f, 0.f, 0.f, 0.f);
    bool alive = false;
    if (i < PRE_N) {
      unsigned long long ck = cb[i];
      if ((unsigned)(ck >> 32) != 0u) { alive = true; v = bb[i]; }
    }
    float ar = (v.z - v.x + 1.0f) * (v.w - v.y + 1.0f);
    int nk0 = s_nk;
    for (int k = 0; k < nk0 && alive; ++k)
      if (sup_test(v, ar, kx1[k], ky1[k], kx2[k], ky2[k], ka[k])) alive = false;
    int checked = nk0;
    for (int w = 0; w < 4; ++w) {
      __syncthreads();
      if (wv == w) {
        int nk = s_nk;
        for (int k = checked; k < nk && alive; ++k)
          if (sup_test(v, ar, kx1[k], ky1[k], kx2[k], ky2[k], ka[k])) alive = false;
        for (int l = 0; l < 64; ++l) {
          int la = __shfl(alive ? 1 : 0, l);
          if (la && nk < POST_N) {
            float bx1 = __shfl(v.x, l), by1 = __shfl(v.y, l);
            float bx2 = __shfl(v.z, l), by2 = __shfl(v.w, l);
            float ba  = __shfl(ar,  l);
            if (lane == l) {
              kx1[nk] = v.x; ky1[nk] = v.y; kx2[nk] = v.z; ky2[nk] = v.w; ka[nk] = ar;
              ob[nk*5+0] = (float)b;
              ob[nk*5+1] = v.x; ob[nk*5+2] = v.y; ob[nk*5+3] = v.z; ob[nk*5+4] = v.w;
            }
            if (lane > l && alive)
              if (sup_test(v, ar, bx1, by1, bx2, by2, ba)) alive = false;
            nk++;
          }
        }
        if (lane == 0) s_nk = nk;
      }
    }
    __syncthreads();
    if (s_nk >= POST_N) break;
  }
  __syncthreads();
  int nk = s_nk;
  for (int r = nk + tid; r < POST_N; r += 256) {
    ob[r*5+0] = (float)b;
    ob[r*5+1] = 0.f; ob[r*5+2] = 0.f; ob[r*5+3] = 0.f; ob[r*5+4] = 0.f;
  }
}

extern "C" void kernel_launch(void* const* d_in, const int* in_sizes, int n_in,
                              void* d_out, int out_size, void* d_ws, size_t ws_size,
                              hipStream_t stream) {
  const float* cls  = (const float*)d_in[0];   // (32, 18, 128, 128)
  const float* dl   = (const float*)d_in[1];   // (32, 36, 128, 128)
  const float* info = (const float*)d_in[2];   // (32, 3)
  float* out = (float*)d_out;                  // (32, 300, 5)
  char* ws = (char*)d_ws;

  // workspace layout (bytes)
  const size_t OFF_KEYS = 0;                        // 32*147456*4 = 18,874,368
  const size_t OFF_H1   = 18874368;                 // 32*4096*4   =    524,288
  const size_t OFF_H2   = 19398656;                 // 32*4096*4   =    524,288
  const size_t OFF_SELA = 19922944;                 // 32*2*4      =        256
  const size_t OFF_THR  = 19923200;                 // 32*4        =        128
  const size_t OFF_CNT  = 19923328;                 // 32*64*4     =      8,192
  const size_t OFF_CAND = 19931520;                 // 32*8192*8   =  2,097,152
  const size_t OFF_BOX  = 22028672;                 // 32*6000*16  =  3,072,000
  const size_t WS_NEED  = 25100672;
  if (ws_size < WS_NEED) return;

  unsigned* keys  = (unsigned*)(ws + OFF_KEYS);
  unsigned* h1    = (unsigned*)(ws + OFF_H1);
  unsigned* h2    = (unsigned*)(ws + OFF_H2);
  unsigned* selA  = (unsigned*)(ws + OFF_SELA);
  unsigned* thr   = (unsigned*)(ws + OFF_THR);
  unsigned* cnt   = (unsigned*)(ws + OFF_CNT);
  unsigned long long* cand = (unsigned long long*)(ws + OFF_CAND);
  float4* boxes   = (float4*)(ws + OFF_BOX);

  // zero h1..cand in one shot (3,154,304 B)
  hipMemsetAsync(ws + OFF_H1, 0, OFF_BOX - OFF_H1, stream);

  dim3 g1(HW / 1024, NB);                 // (16, 32)
  k_keys<<<g1, 256, 0, stream>>>(cls, dl, info, keys);
  dim3 gh(8, NB);
  k_hist1<<<gh, 256, 0, stream>>>(keys, h1);
  k_select1<<<NB, 256, 0, stream>>>(h1, selA);
  k_hist2<<<gh, 256, 0, stream>>>(keys, selA, h2);
  k_select2<<<NB, 256, 0, stream>>>(h2, selA, thr);
  dim3 gg(GX_GATHER, NB);
  k_gather<<<gg, 256, 0, stream>>>(keys, thr, cnt, cand);
  k_sort<<<NB, 1024, 0, stream>>>(cand, dl, info, boxes);
  k_nms<<<NB, 256, 0, stream>>>(cand, boxes, out);
}